// Round 3
// baseline (443.506 us; speedup 1.0000x reference)
//
#include <hip/hip_runtime.h>

#define L 4096
#define CCH 256
#define NB 4

// ---------------------------------------------------------------------------
// Dual conv1x1 GEMM: y1[b,o,l] = b1[o] + sum_c w1[o,c] x[b,c,l]; same for y2.
// Tile 64(o) x 64(l), BK=16, 256 threads, 4x4 per thread.
// ---------------------------------------------------------------------------
__global__ __launch_bounds__(256) void dual_gemm_k(
    const float* __restrict__ x,
    const float* __restrict__ w1, const float* __restrict__ b1,
    const float* __restrict__ w2, const float* __restrict__ b2,
    float* __restrict__ y1, float* __restrict__ y2)
{
    __shared__ float sW1[16][64];
    __shared__ float sW2[16][64];
    __shared__ float sX [16][64];

    const int tid = threadIdx.x;
    const int l0 = blockIdx.x * 64;
    const int o0 = blockIdx.y * 64;
    const int b  = blockIdx.z;
    const int tx = tid & 15, ty = tid >> 4;

    const float* xb = x + (size_t)b * CCH * L;

    float acc1[4][4] = {}; float acc2[4][4] = {};

    const int wo = tid >> 2, wk = (tid & 3) * 4;   // W tile load map
    const int xk = tid >> 4, xl = (tid & 15) * 4;  // X tile load map

    for (int k0 = 0; k0 < CCH; k0 += 16) {
        float4 wv1 = *(const float4*)&w1[(size_t)(o0 + wo) * CCH + k0 + wk];
        float4 wv2 = *(const float4*)&w2[(size_t)(o0 + wo) * CCH + k0 + wk];
        float4 xv  = *(const float4*)&xb[(size_t)(k0 + xk) * L + l0 + xl];
        sW1[wk+0][wo] = wv1.x; sW1[wk+1][wo] = wv1.y; sW1[wk+2][wo] = wv1.z; sW1[wk+3][wo] = wv1.w;
        sW2[wk+0][wo] = wv2.x; sW2[wk+1][wo] = wv2.y; sW2[wk+2][wo] = wv2.z; sW2[wk+3][wo] = wv2.w;
        *(float4*)&sX[xk][xl] = xv;
        __syncthreads();
        #pragma unroll
        for (int k = 0; k < 16; ++k) {
            float4 a1 = *(const float4*)&sW1[k][ty * 4];
            float4 a2 = *(const float4*)&sW2[k][ty * 4];
            float4 bx = *(const float4*)&sX [k][tx * 4];
            float a1v[4] = {a1.x, a1.y, a1.z, a1.w};
            float a2v[4] = {a2.x, a2.y, a2.z, a2.w};
            float bv [4] = {bx.x, bx.y, bx.z, bx.w};
            #pragma unroll
            for (int i = 0; i < 4; ++i)
                #pragma unroll
                for (int j = 0; j < 4; ++j) {
                    acc1[i][j] = fmaf(a1v[i], bv[j], acc1[i][j]);
                    acc2[i][j] = fmaf(a2v[i], bv[j], acc2[i][j]);
                }
        }
        __syncthreads();
    }

    #pragma unroll
    for (int i = 0; i < 4; ++i) {
        int o = o0 + ty * 4 + i;
        float bb1 = b1[o], bb2 = b2[o];
        float4 r1 = make_float4(acc1[i][0] + bb1, acc1[i][1] + bb1, acc1[i][2] + bb1, acc1[i][3] + bb1);
        float4 r2 = make_float4(acc2[i][0] + bb2, acc2[i][1] + bb2, acc2[i][2] + bb2, acc2[i][3] + bb2);
        size_t off = ((size_t)b * CCH + o) * L + l0 + tx * 4;
        *(float4*)&y1[off] = r1;
        *(float4*)&y2[off] = r2;
    }
}

// ---------------------------------------------------------------------------
// Single conv1x1 GEMM (final layer)
// ---------------------------------------------------------------------------
__global__ __launch_bounds__(256) void single_gemm_k(
    const float* __restrict__ x,
    const float* __restrict__ w, const float* __restrict__ bb,
    float* __restrict__ y)
{
    __shared__ float sW[16][64];
    __shared__ float sX[16][64];

    const int tid = threadIdx.x;
    const int l0 = blockIdx.x * 64;
    const int o0 = blockIdx.y * 64;
    const int b  = blockIdx.z;
    const int tx = tid & 15, ty = tid >> 4;

    const float* xb = x + (size_t)b * CCH * L;
    float acc[4][4] = {};

    const int wo = tid >> 2, wk = (tid & 3) * 4;
    const int xk = tid >> 4, xl = (tid & 15) * 4;

    for (int k0 = 0; k0 < CCH; k0 += 16) {
        float4 wv = *(const float4*)&w[(size_t)(o0 + wo) * CCH + k0 + wk];
        float4 xv = *(const float4*)&xb[(size_t)(k0 + xk) * L + l0 + xl];
        sW[wk+0][wo] = wv.x; sW[wk+1][wo] = wv.y; sW[wk+2][wo] = wv.z; sW[wk+3][wo] = wv.w;
        *(float4*)&sX[xk][xl] = xv;
        __syncthreads();
        #pragma unroll
        for (int k = 0; k < 16; ++k) {
            float4 a = *(const float4*)&sW[k][ty * 4];
            float4 bx = *(const float4*)&sX[k][tx * 4];
            float av[4] = {a.x, a.y, a.z, a.w};
            float bv[4] = {bx.x, bx.y, bx.z, bx.w};
            #pragma unroll
            for (int i = 0; i < 4; ++i)
                #pragma unroll
                for (int j = 0; j < 4; ++j)
                    acc[i][j] = fmaf(av[i], bv[j], acc[i][j]);
        }
        __syncthreads();
    }

    #pragma unroll
    for (int i = 0; i < 4; ++i) {
        int o = o0 + ty * 4 + i;
        float b0 = bb[o];
        float4 r = make_float4(acc[i][0] + b0, acc[i][1] + b0, acc[i][2] + b0, acc[i][3] + b0);
        *(float4*)&y[((size_t)b * CCH + o) * L + l0 + tx * 4] = r;
    }
}

// ---------------------------------------------------------------------------
// BatchNorm stats: per channel c over (B, L): scale = g*rstd, shift = be - mu*g*rstd
// ---------------------------------------------------------------------------
__global__ __launch_bounds__(256) void bn_stats_k(
    const float* __restrict__ y, const float* __restrict__ gamma,
    const float* __restrict__ beta,
    float* __restrict__ scale, float* __restrict__ shift)
{
    const int c = blockIdx.x, tid = threadIdx.x;
    float s = 0.f, s2 = 0.f;
    for (int b = 0; b < NB; ++b) {
        const float4* p = (const float4*)(y + ((size_t)b * CCH + c) * L);
        #pragma unroll
        for (int r = 0; r < 4; ++r) {
            float4 v = p[r * 256 + tid];
            s  += v.x + v.y + v.z + v.w;
            s2 += v.x * v.x + v.y * v.y + v.z * v.z + v.w * v.w;
        }
    }
    #pragma unroll
    for (int off = 32; off > 0; off >>= 1) {
        s  += __shfl_down(s, off);
        s2 += __shfl_down(s2, off);
    }
    __shared__ float red[2][4];
    if ((tid & 63) == 0) { red[0][tid >> 6] = s; red[1][tid >> 6] = s2; }
    __syncthreads();
    if (tid == 0) {
        float S  = red[0][0] + red[0][1] + red[0][2] + red[0][3];
        float S2 = red[1][0] + red[1][1] + red[1][2] + red[1][3];
        const float invN = 1.f / (NB * (float)L);
        float mean = S * invN;
        float var  = S2 * invN - mean * mean;
        float rstd = rsqrtf(var + 1e-5f);
        float g = gamma[c];
        scale[c] = g * rstd;
        shift[c] = beta[c] - mean * g * rstd;
    }
}

// ---------------------------------------------------------------------------
// bf16 pack/unpack (RNE)
// ---------------------------------------------------------------------------
__device__ __forceinline__ unsigned short f2bf(float f) {
    unsigned u = __builtin_bit_cast(unsigned, f);
    u += 0x7FFF + ((u >> 16) & 1);
    return (unsigned short)(u >> 16);
}
__device__ __forceinline__ float bf2f(unsigned short h) {
    return __builtin_bit_cast(float, (unsigned)h << 16);
}

// ---------------------------------------------------------------------------
// Attention helpers: gather taps via ONE ds_read_b64 each (k,q,x packed bf16)
// ---------------------------------------------------------------------------
__device__ __forceinline__ void gather9(const ushort4* sKQX, int lp,
                                        float* kv, float* qv, float* xv)
{
    const int base = 9 * lp;
    #pragma unroll
    for (int j = 0; j < 9; ++j) {
        int f = base + j;
        int t = f >> 12;          // which of the 9 unfold taps
        int l = f & 4095;         // spatial position
        int di = (t * 86) >> 8;   // t/3 for t in [0,9)
        int dj = t - di * 3;
        int ii = (l >> 6) + di - 1;
        int jj = (l & 63) + dj - 1;
        bool ok = ((unsigned)ii < 64u) && ((unsigned)jj < 64u);
        int src = ((ii << 6) + jj) & 4095;
        ushort4 v = sKQX[src];
        kv[j] = ok ? bf2f(v.x) : 0.f;
        qv[j] = ok ? bf2f(v.y) : 0.f;
        xv[j] = ok ? bf2f(v.z) : 0.f;
    }
}

__device__ __forceinline__ void soft_scatter(float* sOut, int lp,
                                             const float* kv, const float* qv,
                                             const float* xv)
{
    const float kc = kv[4], qc = qv[4];
    float e[9];
    // logits bounded (post-ReLU BN values, |lg| <~ 60 < 88) -> no max-sub needed
    #pragma unroll
    for (int j = 0; j < 9; ++j)
        e[j] = __expf(kv[j] * qc + kc * qv[j]);
    float s01 = e[0] + e[1], s23 = e[2] + e[3];
    float s45 = e[4] + e[5], s67 = e[6] + e[7];
    float s = ((s01 + s23) + (s45 + s67)) + e[8];
    float inv = __builtin_amdgcn_rcpf(s);
    const int base = 9 * lp;
    #pragma unroll
    for (int j = 0; j < 9; ++j)
        atomicAdd(&sOut[(base + j) & 4095], e[j] * inv * xv[j]);
}

// ---------------------------------------------------------------------------
// Attention: one block per (b,c), 512 threads. (k,q,x) packed as bf16 ushort4
// in one LDS array -> 9 ds_read_b64 + 9 ds_add_f32 per window (vs 36 DS ops).
// 48 KB LDS -> 3 blocks/CU. Writes pre in-place over y2's slice.
// ---------------------------------------------------------------------------
__global__ __launch_bounds__(512, 4) void attention_k(
    const float* __restrict__ x,
    const float* __restrict__ y1,
    const float* y2,
    const float* __restrict__ s1sc, const float* __restrict__ s1sh,
    const float* __restrict__ s2sc, const float* __restrict__ s2sh,
    float* pre)
{
    __shared__ ushort4 sKQX[L];   // 32 KB: (k, q, x, 0) as bf16
    __shared__ float   sOut[L];   // 16 KB

    const int bc = blockIdx.x;
    const int tid = threadIdx.x;
    const int ch = bc & 255;
    const size_t off = (size_t)bc * L;

    const float sc1 = s1sc[ch], sh1 = s1sh[ch];
    const float sc2 = s2sc[ch], sh2 = s2sh[ch];

    const float4* k4 = (const float4*)(y1 + off);
    const float4* q4 = (const float4*)(y2 + off);
    const float4* x4 = (const float4*)(x + off);

    #pragma unroll
    for (int r = 0; r < 2; ++r) {
        int i = r * 512 + tid;
        float4 a = k4[i];
        float4 q = q4[i];
        float4 xx = x4[i];
        float kk[4] = {a.x, a.y, a.z, a.w};
        float qq[4] = {q.x, q.y, q.z, q.w};
        float xv[4] = {xx.x, xx.y, xx.z, xx.w};
        #pragma unroll
        for (int u = 0; u < 4; ++u) {
            ushort4 p;
            p.x = f2bf(fmaxf(fmaf(kk[u], sc1, sh1), 0.f));
            p.y = f2bf(fmaxf(fmaf(qq[u], sc2, sh2), 0.f));
            p.z = f2bf(xv[u]);
            p.w = 0;
            sKQX[i * 4 + u] = p;
        }
        ((float4*)sOut)[i] = make_float4(0.f, 0.f, 0.f, 0.f);
    }
    __syncthreads();

    #pragma unroll
    for (int it = 0; it < 4; ++it) {
        const int lpA = it * 1024 + tid;
        const int lpB = lpA + 512;
        float kvA[9], qvA[9], xvA[9];
        float kvB[9], qvB[9], xvB[9];
        gather9(sKQX, lpA, kvA, qvA, xvA);
        gather9(sKQX, lpB, kvB, qvB, xvB);
        soft_scatter(sOut, lpA, kvA, qvA, xvA);
        soft_scatter(sOut, lpB, kvB, qvB, xvB);
    }
    __syncthreads();

    #pragma unroll
    for (int r = 0; r < 2; ++r) {
        int i = r * 512 + tid;
        ((float4*)(pre + off))[i] = ((const float4*)sOut)[i];
    }
}

// ---------------------------------------------------------------------------
// Final BN apply + ReLU
// ---------------------------------------------------------------------------
__global__ __launch_bounds__(256) void bn_apply_k(
    const float* __restrict__ yf,
    const float* __restrict__ scale, const float* __restrict__ shift,
    float* __restrict__ out)
{
    int i = blockIdx.x * 256 + threadIdx.x;     // float4 index
    int o = (i >> 10) & 255;                    // channel
    float sc = scale[o], sh = shift[o];
    float4 v = ((const float4*)yf)[i];
    v.x = fmaxf(fmaf(v.x, sc, sh), 0.f);
    v.y = fmaxf(fmaf(v.y, sc, sh), 0.f);
    v.z = fmaxf(fmaf(v.z, sc, sh), 0.f);
    v.w = fmaxf(fmaf(v.w, sc, sh), 0.f);
    ((float4*)out)[i] = v;
}

// ---------------------------------------------------------------------------
extern "C" void kernel_launch(void* const* d_in, const int* in_sizes, int n_in,
                              void* d_out, int out_size, void* d_ws, size_t ws_size,
                              hipStream_t stream) {
    const float* x   = (const float*)d_in[0];
    const float* w1  = (const float*)d_in[1];
    const float* b1  = (const float*)d_in[2];
    const float* g1  = (const float*)d_in[3];
    const float* be1 = (const float*)d_in[4];
    const float* w2  = (const float*)d_in[5];
    const float* b2  = (const float*)d_in[6];
    const float* g2  = (const float*)d_in[7];
    const float* be2 = (const float*)d_in[8];
    const float* wf  = (const float*)d_in[9];
    const float* bf  = (const float*)d_in[10];
    const float* gf  = (const float*)d_in[11];
    const float* bef = (const float*)d_in[12];
    float* out = (float*)d_out;

    float* ws = (float*)d_ws;
    const size_t NEL = (size_t)NB * CCH * L;   // 4194304
    float* y1 = ws;                 // raw conv1 out; later reused for yf
    float* y2 = ws + NEL;           // raw conv2 out; later reused for pre
    float* st = ws + 2 * NEL;       // stats: 6 x 256
    float* s1sc = st,        *s1sh = st + 256;
    float* s2sc = st + 512,  *s2sh = st + 768;
    float* sfsc = st + 1024, *sfsh = st + 1280;

    dim3 gg(64, 4, 4);
    dual_gemm_k<<<gg, 256, 0, stream>>>(x, w1, b1, w2, b2, y1, y2);
    bn_stats_k<<<256, 256, 0, stream>>>(y1, g1, be1, s1sc, s1sh);
    bn_stats_k<<<256, 256, 0, stream>>>(y2, g2, be2, s2sc, s2sh);
    attention_k<<<NB * CCH, 512, 0, stream>>>(x, y1, y2, s1sc, s1sh, s2sc, s2sh, /*pre=*/y2);
    single_gemm_k<<<gg, 256, 0, stream>>>(/*pre=*/y2, wf, bf, /*yf=*/y1);
    bn_stats_k<<<256, 256, 0, stream>>>(y1, gf, bef, sfsc, sfsh);
    bn_apply_k<<<4096, 256, 0, stream>>>(y1, sfsc, sfsh, out);
}

// Round 4
// 239.525 us; speedup vs baseline: 1.8516x; 1.8516x over previous
//
#include <hip/hip_runtime.h>

#define L 4096
#define CCH 256
#define NB 4

// ---------------------------------------------------------------------------
// Dual conv1x1 GEMM: y1[b,o,l] = b1[o] + sum_c w1[o,c] x[b,c,l]; same for y2.
// Tile 64(o) x 64(l), BK=16, 256 threads, 4x4 per thread.
// ---------------------------------------------------------------------------
__global__ __launch_bounds__(256) void dual_gemm_k(
    const float* __restrict__ x,
    const float* __restrict__ w1, const float* __restrict__ b1,
    const float* __restrict__ w2, const float* __restrict__ b2,
    float* __restrict__ y1, float* __restrict__ y2)
{
    __shared__ float sW1[16][64];
    __shared__ float sW2[16][64];
    __shared__ float sX [16][64];

    const int tid = threadIdx.x;
    const int l0 = blockIdx.x * 64;
    const int o0 = blockIdx.y * 64;
    const int b  = blockIdx.z;
    const int tx = tid & 15, ty = tid >> 4;

    const float* xb = x + (size_t)b * CCH * L;

    float acc1[4][4] = {}; float acc2[4][4] = {};

    const int wo = tid >> 2, wk = (tid & 3) * 4;   // W tile load map
    const int xk = tid >> 4, xl = (tid & 15) * 4;  // X tile load map

    for (int k0 = 0; k0 < CCH; k0 += 16) {
        float4 wv1 = *(const float4*)&w1[(size_t)(o0 + wo) * CCH + k0 + wk];
        float4 wv2 = *(const float4*)&w2[(size_t)(o0 + wo) * CCH + k0 + wk];
        float4 xv  = *(const float4*)&xb[(size_t)(k0 + xk) * L + l0 + xl];
        sW1[wk+0][wo] = wv1.x; sW1[wk+1][wo] = wv1.y; sW1[wk+2][wo] = wv1.z; sW1[wk+3][wo] = wv1.w;
        sW2[wk+0][wo] = wv2.x; sW2[wk+1][wo] = wv2.y; sW2[wk+2][wo] = wv2.z; sW2[wk+3][wo] = wv2.w;
        *(float4*)&sX[xk][xl] = xv;
        __syncthreads();
        #pragma unroll
        for (int k = 0; k < 16; ++k) {
            float4 a1 = *(const float4*)&sW1[k][ty * 4];
            float4 a2 = *(const float4*)&sW2[k][ty * 4];
            float4 bx = *(const float4*)&sX [k][tx * 4];
            float a1v[4] = {a1.x, a1.y, a1.z, a1.w};
            float a2v[4] = {a2.x, a2.y, a2.z, a2.w};
            float bv [4] = {bx.x, bx.y, bx.z, bx.w};
            #pragma unroll
            for (int i = 0; i < 4; ++i)
                #pragma unroll
                for (int j = 0; j < 4; ++j) {
                    acc1[i][j] = fmaf(a1v[i], bv[j], acc1[i][j]);
                    acc2[i][j] = fmaf(a2v[i], bv[j], acc2[i][j]);
                }
        }
        __syncthreads();
    }

    #pragma unroll
    for (int i = 0; i < 4; ++i) {
        int o = o0 + ty * 4 + i;
        float bb1 = b1[o], bb2 = b2[o];
        float4 r1 = make_float4(acc1[i][0] + bb1, acc1[i][1] + bb1, acc1[i][2] + bb1, acc1[i][3] + bb1);
        float4 r2 = make_float4(acc2[i][0] + bb2, acc2[i][1] + bb2, acc2[i][2] + bb2, acc2[i][3] + bb2);
        size_t off = ((size_t)b * CCH + o) * L + l0 + tx * 4;
        *(float4*)&y1[off] = r1;
        *(float4*)&y2[off] = r2;
    }
}

// ---------------------------------------------------------------------------
// Single conv1x1 GEMM (final layer)
// ---------------------------------------------------------------------------
__global__ __launch_bounds__(256) void single_gemm_k(
    const float* __restrict__ x,
    const float* __restrict__ w, const float* __restrict__ bb,
    float* __restrict__ y)
{
    __shared__ float sW[16][64];
    __shared__ float sX[16][64];

    const int tid = threadIdx.x;
    const int l0 = blockIdx.x * 64;
    const int o0 = blockIdx.y * 64;
    const int b  = blockIdx.z;
    const int tx = tid & 15, ty = tid >> 4;

    const float* xb = x + (size_t)b * CCH * L;
    float acc[4][4] = {};

    const int wo = tid >> 2, wk = (tid & 3) * 4;
    const int xk = tid >> 4, xl = (tid & 15) * 4;

    for (int k0 = 0; k0 < CCH; k0 += 16) {
        float4 wv = *(const float4*)&w[(size_t)(o0 + wo) * CCH + k0 + wk];
        float4 xv = *(const float4*)&xb[(size_t)(k0 + xk) * L + l0 + xl];
        sW[wk+0][wo] = wv.x; sW[wk+1][wo] = wv.y; sW[wk+2][wo] = wv.z; sW[wk+3][wo] = wv.w;
        *(float4*)&sX[xk][xl] = xv;
        __syncthreads();
        #pragma unroll
        for (int k = 0; k < 16; ++k) {
            float4 a = *(const float4*)&sW[k][ty * 4];
            float4 bx = *(const float4*)&sX[k][tx * 4];
            float av[4] = {a.x, a.y, a.z, a.w};
            float bv[4] = {bx.x, bx.y, bx.z, bx.w};
            #pragma unroll
            for (int i = 0; i < 4; ++i)
                #pragma unroll
                for (int j = 0; j < 4; ++j)
                    acc[i][j] = fmaf(av[i], bv[j], acc[i][j]);
        }
        __syncthreads();
    }

    #pragma unroll
    for (int i = 0; i < 4; ++i) {
        int o = o0 + ty * 4 + i;
        float b0 = bb[o];
        float4 r = make_float4(acc[i][0] + b0, acc[i][1] + b0, acc[i][2] + b0, acc[i][3] + b0);
        *(float4*)&y[((size_t)b * CCH + o) * L + l0 + tx * 4] = r;
    }
}

// ---------------------------------------------------------------------------
// BatchNorm stats: per channel c over (B, L): scale = g*rstd, shift = be - mu*g*rstd
// ---------------------------------------------------------------------------
__global__ __launch_bounds__(256) void bn_stats_k(
    const float* __restrict__ y, const float* __restrict__ gamma,
    const float* __restrict__ beta,
    float* __restrict__ scale, float* __restrict__ shift)
{
    const int c = blockIdx.x, tid = threadIdx.x;
    float s = 0.f, s2 = 0.f;
    for (int b = 0; b < NB; ++b) {
        const float4* p = (const float4*)(y + ((size_t)b * CCH + c) * L);
        #pragma unroll
        for (int r = 0; r < 4; ++r) {
            float4 v = p[r * 256 + tid];
            s  += v.x + v.y + v.z + v.w;
            s2 += v.x * v.x + v.y * v.y + v.z * v.z + v.w * v.w;
        }
    }
    #pragma unroll
    for (int off = 32; off > 0; off >>= 1) {
        s  += __shfl_down(s, off);
        s2 += __shfl_down(s2, off);
    }
    __shared__ float red[2][4];
    if ((tid & 63) == 0) { red[0][tid >> 6] = s; red[1][tid >> 6] = s2; }
    __syncthreads();
    if (tid == 0) {
        float S  = red[0][0] + red[0][1] + red[0][2] + red[0][3];
        float S2 = red[1][0] + red[1][1] + red[1][2] + red[1][3];
        const float invN = 1.f / (NB * (float)L);
        float mean = S * invN;
        float var  = S2 * invN - mean * mean;
        float rstd = rsqrtf(var + 1e-5f);
        float g = gamma[c];
        scale[c] = g * rstd;
        shift[c] = beta[c] - mean * g * rstd;
    }
}

// ---------------------------------------------------------------------------
// Attention, two-phase, NO LDS atomics.
// Phase 1: per window lp, softmax denominator -> sInv[lp]  (stride-9 b32
//          gathers, conflict-free; one plain write).
// Phase 2: per output l: out[l] = sum_t e(t,l) * sInv[lp(t,l)] * x(t,l),
//          all reads stride-1 or broadcast, accumulate in registers,
//          coalesced global write. One block per (b,c), 512 threads.
// LDS = 64 KB -> 2 blocks/CU.
// ---------------------------------------------------------------------------
__global__ __launch_bounds__(512, 4) void attention_k(
    const float* __restrict__ x,
    const float* __restrict__ y1,
    const float* __restrict__ y2,
    const float* __restrict__ s1sc, const float* __restrict__ s1sh,
    const float* __restrict__ s2sc, const float* __restrict__ s2sh,
    float* __restrict__ pre)
{
    __shared__ float sK[L];
    __shared__ float sQ[L];
    __shared__ float sXv[L];
    __shared__ float sInv[L];

    const int bc = blockIdx.x;
    const int tid = threadIdx.x;
    const int ch = bc & 255;
    const size_t off = (size_t)bc * L;

    const float sc1 = s1sc[ch], sh1 = s1sh[ch];
    const float sc2 = s2sc[ch], sh2 = s2sh[ch];

    const float4* k4 = (const float4*)(y1 + off);
    const float4* q4 = (const float4*)(y2 + off);
    const float4* x4 = (const float4*)(x + off);

    #pragma unroll
    for (int r = 0; r < 2; ++r) {
        int i = r * 512 + tid;
        float4 a = k4[i];
        a.x = fmaxf(fmaf(a.x, sc1, sh1), 0.f);
        a.y = fmaxf(fmaf(a.y, sc1, sh1), 0.f);
        a.z = fmaxf(fmaf(a.z, sc1, sh1), 0.f);
        a.w = fmaxf(fmaf(a.w, sc1, sh1), 0.f);
        ((float4*)sK)[i] = a;
        float4 q = q4[i];
        q.x = fmaxf(fmaf(q.x, sc2, sh2), 0.f);
        q.y = fmaxf(fmaf(q.y, sc2, sh2), 0.f);
        q.z = fmaxf(fmaf(q.z, sc2, sh2), 0.f);
        q.w = fmaxf(fmaf(q.w, sc2, sh2), 0.f);
        ((float4*)sQ)[i] = q;
        ((float4*)sXv)[i] = x4[i];
    }
    __syncthreads();

    // ---- Phase 1: softmax denominators --------------------------------
    #pragma unroll
    for (int r = 0; r < 8; ++r) {
        const int lp = r * 512 + tid;
        const int base = 9 * lp;
        float kv[9], qv[9];
        #pragma unroll
        for (int j = 0; j < 9; ++j) {
            int f = base + j;
            int t = f >> 12;
            int l = f & 4095;
            int di = (t * 86) >> 8;     // t/3
            int dj = t - di * 3;
            int ii = (l >> 6) + di - 1;
            int jj = (l & 63) + dj - 1;
            bool ok = ((unsigned)ii < 64u) && ((unsigned)jj < 64u);
            int src = ((ii << 6) + jj) & 4095;
            float kj = sK[src], qj = sQ[src];
            kv[j] = ok ? kj : 0.f;
            qv[j] = ok ? qj : 0.f;
        }
        const float kc = kv[4], qc = qv[4];
        float s01 = __expf(kv[0] * qc + kc * qv[0]) + __expf(kv[1] * qc + kc * qv[1]);
        float s23 = __expf(kv[2] * qc + kc * qv[2]) + __expf(kv[3] * qc + kc * qv[3]);
        float s45 = __expf(kv[4] * qc + kc * qv[4]) + __expf(kv[5] * qc + kc * qv[5]);
        float s67 = __expf(kv[6] * qc + kc * qv[6]) + __expf(kv[7] * qc + kc * qv[7]);
        float s = ((s01 + s23) + (s45 + s67)) + __expf(kv[8] * qc + kc * qv[8]);
        sInv[lp] = __builtin_amdgcn_rcpf(s);
    }
    __syncthreads();

    // ---- Phase 2: per-output gather-accumulate ------------------------
    #pragma unroll
    for (int r = 0; r < 8; ++r) {
        const int l = r * 512 + tid;
        const int li = l >> 6, lj = l & 63;
        float acc = 0.f;
        #pragma unroll
        for (int t = 0; t < 9; ++t) {
            const int f = (t << 12) + l;
            const unsigned lp = (unsigned)f / 9u;           // magic-mul
            // this element's position: tap t (compile-time), spatial l
            const int di = t / 3, dj = t % 3;               // constants
            int ii = li + di - 1;
            int jj = lj + dj - 1;
            bool ok = ((unsigned)ii < 64u) && ((unsigned)jj < 64u);
            int src = ((ii << 6) + jj) & 4095;
            float kj = sK[src], qj = sQ[src], xj = sXv[src];
            kj = ok ? kj : 0.f; qj = ok ? qj : 0.f; xj = ok ? xj : 0.f;
            // center (element 4) of window lp: its own flat decode
            int fc = 9 * (int)lp + 4;
            int tc = fc >> 12;
            int lc = fc & 4095;
            int dci = (tc * 86) >> 8;
            int dcj = tc - dci * 3;
            int ci = (lc >> 6) + dci - 1;
            int cj = (lc & 63) + dcj - 1;
            bool okc = ((unsigned)ci < 64u) && ((unsigned)cj < 64u);
            int csrc = ((ci << 6) + cj) & 4095;
            float kc = sK[csrc], qc = sQ[csrc];
            kc = okc ? kc : 0.f; qc = okc ? qc : 0.f;
            float e = __expf(kj * qc + kc * qj);
            acc = fmaf(e * sInv[lp], xj, acc);
        }
        pre[off + l] = acc;
    }
}

// ---------------------------------------------------------------------------
// Final BN apply + ReLU
// ---------------------------------------------------------------------------
__global__ __launch_bounds__(256) void bn_apply_k(
    const float* __restrict__ yf,
    const float* __restrict__ scale, const float* __restrict__ shift,
    float* __restrict__ out)
{
    int i = blockIdx.x * 256 + threadIdx.x;     // float4 index
    int o = (i >> 10) & 255;                    // channel
    float sc = scale[o], sh = shift[o];
    float4 v = ((const float4*)yf)[i];
    v.x = fmaxf(fmaf(v.x, sc, sh), 0.f);
    v.y = fmaxf(fmaf(v.y, sc, sh), 0.f);
    v.z = fmaxf(fmaf(v.z, sc, sh), 0.f);
    v.w = fmaxf(fmaf(v.w, sc, sh), 0.f);
    ((float4*)out)[i] = v;
}

// ---------------------------------------------------------------------------
extern "C" void kernel_launch(void* const* d_in, const int* in_sizes, int n_in,
                              void* d_out, int out_size, void* d_ws, size_t ws_size,
                              hipStream_t stream) {
    const float* x   = (const float*)d_in[0];
    const float* w1  = (const float*)d_in[1];
    const float* b1  = (const float*)d_in[2];
    const float* g1  = (const float*)d_in[3];
    const float* be1 = (const float*)d_in[4];
    const float* w2  = (const float*)d_in[5];
    const float* b2  = (const float*)d_in[6];
    const float* g2  = (const float*)d_in[7];
    const float* be2 = (const float*)d_in[8];
    const float* wf  = (const float*)d_in[9];
    const float* bf  = (const float*)d_in[10];
    const float* gf  = (const float*)d_in[11];
    const float* bef = (const float*)d_in[12];
    float* out = (float*)d_out;

    float* ws = (float*)d_ws;
    const size_t NEL = (size_t)NB * CCH * L;   // 4194304
    float* y1 = ws;                 // raw conv1 out; later reused for yf
    float* y2 = ws + NEL;           // raw conv2 out; later reused for pre
    float* st = ws + 2 * NEL;       // stats: 6 x 256
    float* s1sc = st,        *s1sh = st + 256;
    float* s2sc = st + 512,  *s2sh = st + 768;
    float* sfsc = st + 1024, *sfsh = st + 1280;

    dim3 gg(64, 4, 4);
    dual_gemm_k<<<gg, 256, 0, stream>>>(x, w1, b1, w2, b2, y1, y2);
    bn_stats_k<<<256, 256, 0, stream>>>(y1, g1, be1, s1sc, s1sh);
    bn_stats_k<<<256, 256, 0, stream>>>(y2, g2, be2, s2sc, s2sh);
    attention_k<<<NB * CCH, 512, 0, stream>>>(x, y1, y2, s1sc, s1sh, s2sc, s2sh, /*pre=*/y2);
    single_gemm_k<<<gg, 256, 0, stream>>>(/*pre=*/y2, wf, bf, /*yf=*/y1);
    bn_stats_k<<<256, 256, 0, stream>>>(y1, gf, bef, sfsc, sfsh);
    bn_apply_k<<<4096, 256, 0, stream>>>(y1, sfsc, sfsh, out);
}

// Round 5
// 194.995 us; speedup vs baseline: 2.2744x; 1.2284x over previous
//
#include <hip/hip_runtime.h>

#define L 4096
#define CCH 256
#define NB 4
#define KP 40   // padded LDS row length (32 k + 8 pad) in bf16 elems; 80 B rows

typedef __attribute__((ext_vector_type(8))) short short8;
typedef __attribute__((ext_vector_type(4))) float f32x4;

__device__ __forceinline__ unsigned short f2bf(float f) {
    unsigned u = __builtin_bit_cast(unsigned, f);
    u += 0x7FFF + ((u >> 16) & 1);
    return (unsigned short)(u >> 16);
}

// ---------------------------------------------------------------------------
// Dual conv1x1 via bf16 MFMA: y{1,2}[b,o,l] = b{1,2}[o] + sum_c w{1,2}[o,c] x[b,c,l]
// Block tile: 128 o x 64 l, 256 threads (4 waves), wave = 32o x 64l per GEMM.
// K-loop: 8 slabs of K=32; one mfma_f32_16x16x32_bf16 per (gemm, io, jl).
// ---------------------------------------------------------------------------
__global__ __launch_bounds__(256, 2) void dual_gemm_k(
    const float* __restrict__ x,
    const float* __restrict__ w1, const float* __restrict__ b1,
    const float* __restrict__ w2, const float* __restrict__ b2,
    float* __restrict__ y1, float* __restrict__ y2)
{
    __shared__ short sA1[128 * KP];
    __shared__ short sA2[128 * KP];
    __shared__ short sB [64 * KP];

    const int tid = threadIdx.x;
    const int l0 = blockIdx.x * 64;
    const int o0 = blockIdx.y * 128;
    const int b  = blockIdx.z;

    const int wv = tid >> 6;          // wave 0..3
    const int lane = tid & 63;
    const int m = lane & 15;          // col within frag
    const int quad = lane >> 4;       // 0..3

    const float* xb = x + (size_t)b * CCH * L;

    // staging maps
    const int sl = tid & 63, soct = tid >> 6;     // x: l, k-octet
    const int sr = tid & 127, sh = tid >> 7;      // w: o-row, k-half(16)

    f32x4 acc1[2][4] = {{{0.f,0.f,0.f,0.f}}};
    f32x4 acc2[2][4] = {{{0.f,0.f,0.f,0.f}}};
    #pragma unroll
    for (int io = 0; io < 2; ++io)
        #pragma unroll
        for (int jl = 0; jl < 4; ++jl) {
            acc1[io][jl] = (f32x4){0.f,0.f,0.f,0.f};
            acc2[io][jl] = (f32x4){0.f,0.f,0.f,0.f};
        }

    for (int s = 0; s < 8; ++s) {
        const int k0 = s * 32;
        __syncthreads();
        // --- stage x slab [k0..k0+31][l0..l0+63] -> sB[l][k] (transposed)
        {
            const float* xs = xb + (size_t)(k0 + soct * 8) * L + l0 + sl;
            short8 v;
            #pragma unroll
            for (int j = 0; j < 8; ++j) v[j] = (short)f2bf(xs[(size_t)j * L]);
            *(short8*)&sB[sl * KP + soct * 8] = v;
        }
        // --- stage w1/w2 slab [o0..o0+127][k0..k0+31] -> sA[r][k]
        {
            const float4* wp = (const float4*)&w1[(size_t)(o0 + sr) * CCH + k0 + sh * 16];
            float4 c0 = wp[0], c1 = wp[1], c2 = wp[2], c3 = wp[3];
            short8 p0 = {(short)f2bf(c0.x),(short)f2bf(c0.y),(short)f2bf(c0.z),(short)f2bf(c0.w),
                         (short)f2bf(c1.x),(short)f2bf(c1.y),(short)f2bf(c1.z),(short)f2bf(c1.w)};
            short8 p1 = {(short)f2bf(c2.x),(short)f2bf(c2.y),(short)f2bf(c2.z),(short)f2bf(c2.w),
                         (short)f2bf(c3.x),(short)f2bf(c3.y),(short)f2bf(c3.z),(short)f2bf(c3.w)};
            *(short8*)&sA1[sr * KP + sh * 16]     = p0;
            *(short8*)&sA1[sr * KP + sh * 16 + 8] = p1;
            const float4* wq = (const float4*)&w2[(size_t)(o0 + sr) * CCH + k0 + sh * 16];
            float4 d0 = wq[0], d1 = wq[1], d2 = wq[2], d3 = wq[3];
            short8 q0 = {(short)f2bf(d0.x),(short)f2bf(d0.y),(short)f2bf(d0.z),(short)f2bf(d0.w),
                         (short)f2bf(d1.x),(short)f2bf(d1.y),(short)f2bf(d1.z),(short)f2bf(d1.w)};
            short8 q1 = {(short)f2bf(d2.x),(short)f2bf(d2.y),(short)f2bf(d2.z),(short)f2bf(d2.w),
                         (short)f2bf(d3.x),(short)f2bf(d3.y),(short)f2bf(d3.z),(short)f2bf(d3.w)};
            *(short8*)&sA2[sr * KP + sh * 16]     = q0;
            *(short8*)&sA2[sr * KP + sh * 16 + 8] = q1;
        }
        __syncthreads();
        // --- compute: 16 MFMA per wave
        short8 a1[2], a2[2], bf[4];
        #pragma unroll
        for (int io = 0; io < 2; ++io) {
            a1[io] = *(const short8*)&sA1[(wv * 32 + io * 16 + m) * KP + quad * 8];
            a2[io] = *(const short8*)&sA2[(wv * 32 + io * 16 + m) * KP + quad * 8];
        }
        #pragma unroll
        for (int jl = 0; jl < 4; ++jl)
            bf[jl] = *(const short8*)&sB[(jl * 16 + m) * KP + quad * 8];
        #pragma unroll
        for (int io = 0; io < 2; ++io)
            #pragma unroll
            for (int jl = 0; jl < 4; ++jl) {
                acc1[io][jl] = __builtin_amdgcn_mfma_f32_16x16x32_bf16(a1[io], bf[jl], acc1[io][jl], 0, 0, 0);
                acc2[io][jl] = __builtin_amdgcn_mfma_f32_16x16x32_bf16(a2[io], bf[jl], acc2[io][jl], 0, 0, 0);
            }
    }

    // epilogue: C/D layout col=lane&15, row=quad*4+reg
    #pragma unroll
    for (int io = 0; io < 2; ++io)
        #pragma unroll
        for (int reg = 0; reg < 4; ++reg) {
            const int o = o0 + wv * 32 + io * 16 + quad * 4 + reg;
            const float bb1 = b1[o], bb2 = b2[o];
            const size_t ro = ((size_t)b * CCH + o) * L + l0 + m;
            #pragma unroll
            for (int jl = 0; jl < 4; ++jl) {
                y1[ro + jl * 16] = acc1[io][jl][reg] + bb1;
                y2[ro + jl * 16] = acc2[io][jl][reg] + bb2;
            }
        }
}

// ---------------------------------------------------------------------------
// Single conv1x1 via bf16 MFMA (final layer)
// ---------------------------------------------------------------------------
__global__ __launch_bounds__(256, 2) void single_gemm_k(
    const float* __restrict__ x,
    const float* __restrict__ w, const float* __restrict__ bb,
    float* __restrict__ y)
{
    __shared__ short sA[128 * KP];
    __shared__ short sB[64 * KP];

    const int tid = threadIdx.x;
    const int l0 = blockIdx.x * 64;
    const int o0 = blockIdx.y * 128;
    const int b  = blockIdx.z;

    const int wv = tid >> 6;
    const int lane = tid & 63;
    const int m = lane & 15;
    const int quad = lane >> 4;

    const float* xb = x + (size_t)b * CCH * L;

    const int sl = tid & 63, soct = tid >> 6;
    const int sr = tid & 127, sh = tid >> 7;

    f32x4 acc[2][4];
    #pragma unroll
    for (int io = 0; io < 2; ++io)
        #pragma unroll
        for (int jl = 0; jl < 4; ++jl)
            acc[io][jl] = (f32x4){0.f,0.f,0.f,0.f};

    for (int s = 0; s < 8; ++s) {
        const int k0 = s * 32;
        __syncthreads();
        {
            const float* xs = xb + (size_t)(k0 + soct * 8) * L + l0 + sl;
            short8 v;
            #pragma unroll
            for (int j = 0; j < 8; ++j) v[j] = (short)f2bf(xs[(size_t)j * L]);
            *(short8*)&sB[sl * KP + soct * 8] = v;
        }
        {
            const float4* wp = (const float4*)&w[(size_t)(o0 + sr) * CCH + k0 + sh * 16];
            float4 c0 = wp[0], c1 = wp[1], c2 = wp[2], c3 = wp[3];
            short8 p0 = {(short)f2bf(c0.x),(short)f2bf(c0.y),(short)f2bf(c0.z),(short)f2bf(c0.w),
                         (short)f2bf(c1.x),(short)f2bf(c1.y),(short)f2bf(c1.z),(short)f2bf(c1.w)};
            short8 p1 = {(short)f2bf(c2.x),(short)f2bf(c2.y),(short)f2bf(c2.z),(short)f2bf(c2.w),
                         (short)f2bf(c3.x),(short)f2bf(c3.y),(short)f2bf(c3.z),(short)f2bf(c3.w)};
            *(short8*)&sA[sr * KP + sh * 16]     = p0;
            *(short8*)&sA[sr * KP + sh * 16 + 8] = p1;
        }
        __syncthreads();
        short8 a[2], bf[4];
        #pragma unroll
        for (int io = 0; io < 2; ++io)
            a[io] = *(const short8*)&sA[(wv * 32 + io * 16 + m) * KP + quad * 8];
        #pragma unroll
        for (int jl = 0; jl < 4; ++jl)
            bf[jl] = *(const short8*)&sB[(jl * 16 + m) * KP + quad * 8];
        #pragma unroll
        for (int io = 0; io < 2; ++io)
            #pragma unroll
            for (int jl = 0; jl < 4; ++jl)
                acc[io][jl] = __builtin_amdgcn_mfma_f32_16x16x32_bf16(a[io], bf[jl], acc[io][jl], 0, 0, 0);
    }

    #pragma unroll
    for (int io = 0; io < 2; ++io)
        #pragma unroll
        for (int reg = 0; reg < 4; ++reg) {
            const int o = o0 + wv * 32 + io * 16 + quad * 4 + reg;
            const float b0 = bb[o];
            const size_t ro = ((size_t)b * CCH + o) * L + l0 + m;
            #pragma unroll
            for (int jl = 0; jl < 4; ++jl)
                y[ro + jl * 16] = acc[io][jl][reg] + b0;
        }
}

// ---------------------------------------------------------------------------
// BatchNorm stats: per channel c over (B, L): scale = g*rstd, shift = be - mu*g*rstd
// ---------------------------------------------------------------------------
__global__ __launch_bounds__(256) void bn_stats_k(
    const float* __restrict__ y, const float* __restrict__ gamma,
    const float* __restrict__ beta,
    float* __restrict__ scale, float* __restrict__ shift)
{
    const int c = blockIdx.x, tid = threadIdx.x;
    float s = 0.f, s2 = 0.f;
    for (int b = 0; b < NB; ++b) {
        const float4* p = (const float4*)(y + ((size_t)b * CCH + c) * L);
        #pragma unroll
        for (int r = 0; r < 4; ++r) {
            float4 v = p[r * 256 + tid];
            s  += v.x + v.y + v.z + v.w;
            s2 += v.x * v.x + v.y * v.y + v.z * v.z + v.w * v.w;
        }
    }
    #pragma unroll
    for (int off = 32; off > 0; off >>= 1) {
        s  += __shfl_down(s, off);
        s2 += __shfl_down(s2, off);
    }
    __shared__ float red[2][4];
    if ((tid & 63) == 0) { red[0][tid >> 6] = s; red[1][tid >> 6] = s2; }
    __syncthreads();
    if (tid == 0) {
        float S  = red[0][0] + red[0][1] + red[0][2] + red[0][3];
        float S2 = red[1][0] + red[1][1] + red[1][2] + red[1][3];
        const float invN = 1.f / (NB * (float)L);
        float mean = S * invN;
        float var  = S2 * invN - mean * mean;
        float rstd = rsqrtf(var + 1e-5f);
        float g = gamma[c];
        scale[c] = g * rstd;
        shift[c] = beta[c] - mean * g * rstd;
    }
}

// ---------------------------------------------------------------------------
// Attention, two-phase, NO LDS atomics (unchanged from R4).
// ---------------------------------------------------------------------------
__global__ __launch_bounds__(512, 4) void attention_k(
    const float* __restrict__ x,
    const float* __restrict__ y1,
    const float* __restrict__ y2,
    const float* __restrict__ s1sc, const float* __restrict__ s1sh,
    const float* __restrict__ s2sc, const float* __restrict__ s2sh,
    float* __restrict__ pre)
{
    __shared__ float sK[L];
    __shared__ float sQ[L];
    __shared__ float sXv[L];
    __shared__ float sInv[L];

    const int bc = blockIdx.x;
    const int tid = threadIdx.x;
    const int ch = bc & 255;
    const size_t off = (size_t)bc * L;

    const float sc1 = s1sc[ch], sh1 = s1sh[ch];
    const float sc2 = s2sc[ch], sh2 = s2sh[ch];

    const float4* k4 = (const float4*)(y1 + off);
    const float4* q4 = (const float4*)(y2 + off);
    const float4* x4 = (const float4*)(x + off);

    #pragma unroll
    for (int r = 0; r < 2; ++r) {
        int i = r * 512 + tid;
        float4 a = k4[i];
        a.x = fmaxf(fmaf(a.x, sc1, sh1), 0.f);
        a.y = fmaxf(fmaf(a.y, sc1, sh1), 0.f);
        a.z = fmaxf(fmaf(a.z, sc1, sh1), 0.f);
        a.w = fmaxf(fmaf(a.w, sc1, sh1), 0.f);
        ((float4*)sK)[i] = a;
        float4 q = q4[i];
        q.x = fmaxf(fmaf(q.x, sc2, sh2), 0.f);
        q.y = fmaxf(fmaf(q.y, sc2, sh2), 0.f);
        q.z = fmaxf(fmaf(q.z, sc2, sh2), 0.f);
        q.w = fmaxf(fmaf(q.w, sc2, sh2), 0.f);
        ((float4*)sQ)[i] = q;
        ((float4*)sXv)[i] = x4[i];
    }
    __syncthreads();

    // ---- Phase 1: softmax denominators --------------------------------
    #pragma unroll
    for (int r = 0; r < 8; ++r) {
        const int lp = r * 512 + tid;
        const int base = 9 * lp;
        float kv[9], qv[9];
        #pragma unroll
        for (int j = 0; j < 9; ++j) {
            int f = base + j;
            int t = f >> 12;
            int l = f & 4095;
            int di = (t * 86) >> 8;     // t/3
            int dj = t - di * 3;
            int ii = (l >> 6) + di - 1;
            int jj = (l & 63) + dj - 1;
            bool ok = ((unsigned)ii < 64u) && ((unsigned)jj < 64u);
            int src = ((ii << 6) + jj) & 4095;
            float kj = sK[src], qj = sQ[src];
            kv[j] = ok ? kj : 0.f;
            qv[j] = ok ? qj : 0.f;
        }
        const float kc = kv[4], qc = qv[4];
        float s01 = __expf(kv[0] * qc + kc * qv[0]) + __expf(kv[1] * qc + kc * qv[1]);
        float s23 = __expf(kv[2] * qc + kc * qv[2]) + __expf(kv[3] * qc + kc * qv[3]);
        float s45 = __expf(kv[4] * qc + kc * qv[4]) + __expf(kv[5] * qc + kc * qv[5]);
        float s67 = __expf(kv[6] * qc + kc * qv[6]) + __expf(kv[7] * qc + kc * qv[7]);
        float s = ((s01 + s23) + (s45 + s67)) + __expf(kv[8] * qc + kc * qv[8]);
        sInv[lp] = __builtin_amdgcn_rcpf(s);
    }
    __syncthreads();

    // ---- Phase 2: per-output gather-accumulate ------------------------
    #pragma unroll
    for (int r = 0; r < 8; ++r) {
        const int l = r * 512 + tid;
        const int li = l >> 6, lj = l & 63;
        float acc = 0.f;
        #pragma unroll
        for (int t = 0; t < 9; ++t) {
            const int f = (t << 12) + l;
            const unsigned lp = (unsigned)f / 9u;
            const int di = t / 3, dj = t % 3;
            int ii = li + di - 1;
            int jj = lj + dj - 1;
            bool ok = ((unsigned)ii < 64u) && ((unsigned)jj < 64u);
            int src = ((ii << 6) + jj) & 4095;
            float kj = sK[src], qj = sQ[src], xj = sXv[src];
            kj = ok ? kj : 0.f; qj = ok ? qj : 0.f; xj = ok ? xj : 0.f;
            int fc = 9 * (int)lp + 4;
            int tc = fc >> 12;
            int lc = fc & 4095;
            int dci = (tc * 86) >> 8;
            int dcj = tc - dci * 3;
            int ci = (lc >> 6) + dci - 1;
            int cj = (lc & 63) + dcj - 1;
            bool okc = ((unsigned)ci < 64u) && ((unsigned)cj < 64u);
            int csrc = ((ci << 6) + cj) & 4095;
            float kc = sK[csrc], qc = sQ[csrc];
            kc = okc ? kc : 0.f; qc = okc ? qc : 0.f;
            float e = __expf(kj * qc + kc * qj);
            acc = fmaf(e * sInv[lp], xj, acc);
        }
        pre[off + l] = acc;
    }
}

// ---------------------------------------------------------------------------
// Final BN apply + ReLU
// ---------------------------------------------------------------------------
__global__ __launch_bounds__(256) void bn_apply_k(
    const float* __restrict__ yf,
    const float* __restrict__ scale, const float* __restrict__ shift,
    float* __restrict__ out)
{
    int i = blockIdx.x * 256 + threadIdx.x;     // float4 index
    int o = (i >> 10) & 255;                    // channel
    float sc = scale[o], sh = shift[o];
    float4 v = ((const float4*)yf)[i];
    v.x = fmaxf(fmaf(v.x, sc, sh), 0.f);
    v.y = fmaxf(fmaf(v.y, sc, sh), 0.f);
    v.z = fmaxf(fmaf(v.z, sc, sh), 0.f);
    v.w = fmaxf(fmaf(v.w, sc, sh), 0.f);
    ((float4*)out)[i] = v;
}

// ---------------------------------------------------------------------------
extern "C" void kernel_launch(void* const* d_in, const int* in_sizes, int n_in,
                              void* d_out, int out_size, void* d_ws, size_t ws_size,
                              hipStream_t stream) {
    const float* x   = (const float*)d_in[0];
    const float* w1  = (const float*)d_in[1];
    const float* b1  = (const float*)d_in[2];
    const float* g1  = (const float*)d_in[3];
    const float* be1 = (const float*)d_in[4];
    const float* w2  = (const float*)d_in[5];
    const float* b2  = (const float*)d_in[6];
    const float* g2  = (const float*)d_in[7];
    const float* be2 = (const float*)d_in[8];
    const float* wf  = (const float*)d_in[9];
    const float* bf  = (const float*)d_in[10];
    const float* gf  = (const float*)d_in[11];
    const float* bef = (const float*)d_in[12];
    float* out = (float*)d_out;

    float* ws = (float*)d_ws;
    const size_t NEL = (size_t)NB * CCH * L;   // 4194304
    float* y1 = ws;                 // conv1 out; later reused for yf
    float* y2 = ws + NEL;           // conv2 out; later reused for pre
    float* st = ws + 2 * NEL;       // stats: 6 x 256
    float* s1sc = st,        *s1sh = st + 256;
    float* s2sc = st + 512,  *s2sh = st + 768;
    float* sfsc = st + 1024, *sfsh = st + 1280;

    dim3 gg(64, 2, 4);
    dual_gemm_k<<<gg, 256, 0, stream>>>(x, w1, b1, w2, b2, y1, y2);
    bn_stats_k<<<256, 256, 0, stream>>>(y1, g1, be1, s1sc, s1sh);
    bn_stats_k<<<256, 256, 0, stream>>>(y2, g2, be2, s2sc, s2sh);
    attention_k<<<NB * CCH, 512, 0, stream>>>(x, y1, y2, s1sc, s1sh, s2sc, s2sh, /*pre=*/y2);
    single_gemm_k<<<gg, 256, 0, stream>>>(/*pre=*/y2, wf, bf, /*yf=*/y1);
    bn_stats_k<<<256, 256, 0, stream>>>(y1, gf, bef, sfsc, sfsh);
    bn_apply_k<<<4096, 256, 0, stream>>>(y1, sfsc, sfsh, out);
}

// Round 6
// 186.437 us; speedup vs baseline: 2.3788x; 1.0459x over previous
//
#include <hip/hip_runtime.h>

#define L 4096
#define CCH 256
#define NB 4
#define KP 40   // padded LDS row length (32 k + 8 pad) in bf16 elems; 80 B rows

typedef __attribute__((ext_vector_type(8))) short short8;
typedef __attribute__((ext_vector_type(4))) float f32x4;

__device__ __forceinline__ unsigned short f2bf(float f) {
    unsigned u = __builtin_bit_cast(unsigned, f);
    u += 0x7FFF + ((u >> 16) & 1);
    return (unsigned short)(u >> 16);
}
__device__ __forceinline__ float bflo(unsigned w) {
    return __builtin_bit_cast(float, w << 16);
}
__device__ __forceinline__ float bfhi(unsigned w) {
    return __builtin_bit_cast(float, w & 0xFFFF0000u);
}

// ---------------------------------------------------------------------------
// Dual conv1x1 via bf16 MFMA (unchanged from R5)
// ---------------------------------------------------------------------------
__global__ __launch_bounds__(256, 2) void dual_gemm_k(
    const float* __restrict__ x,
    const float* __restrict__ w1, const float* __restrict__ b1,
    const float* __restrict__ w2, const float* __restrict__ b2,
    float* __restrict__ y1, float* __restrict__ y2)
{
    __shared__ short sA1[128 * KP];
    __shared__ short sA2[128 * KP];
    __shared__ short sB [64 * KP];

    const int tid = threadIdx.x;
    const int l0 = blockIdx.x * 64;
    const int o0 = blockIdx.y * 128;
    const int b  = blockIdx.z;

    const int wv = tid >> 6;
    const int lane = tid & 63;
    const int m = lane & 15;
    const int quad = lane >> 4;

    const float* xb = x + (size_t)b * CCH * L;

    const int sl = tid & 63, soct = tid >> 6;
    const int sr = tid & 127, sh = tid >> 7;

    f32x4 acc1[2][4], acc2[2][4];
    #pragma unroll
    for (int io = 0; io < 2; ++io)
        #pragma unroll
        for (int jl = 0; jl < 4; ++jl) {
            acc1[io][jl] = (f32x4){0.f,0.f,0.f,0.f};
            acc2[io][jl] = (f32x4){0.f,0.f,0.f,0.f};
        }

    for (int s = 0; s < 8; ++s) {
        const int k0 = s * 32;
        __syncthreads();
        {
            const float* xs = xb + (size_t)(k0 + soct * 8) * L + l0 + sl;
            short8 v;
            #pragma unroll
            for (int j = 0; j < 8; ++j) v[j] = (short)f2bf(xs[(size_t)j * L]);
            *(short8*)&sB[sl * KP + soct * 8] = v;
        }
        {
            const float4* wp = (const float4*)&w1[(size_t)(o0 + sr) * CCH + k0 + sh * 16];
            float4 c0 = wp[0], c1 = wp[1], c2 = wp[2], c3 = wp[3];
            short8 p0 = {(short)f2bf(c0.x),(short)f2bf(c0.y),(short)f2bf(c0.z),(short)f2bf(c0.w),
                         (short)f2bf(c1.x),(short)f2bf(c1.y),(short)f2bf(c1.z),(short)f2bf(c1.w)};
            short8 p1 = {(short)f2bf(c2.x),(short)f2bf(c2.y),(short)f2bf(c2.z),(short)f2bf(c2.w),
                         (short)f2bf(c3.x),(short)f2bf(c3.y),(short)f2bf(c3.z),(short)f2bf(c3.w)};
            *(short8*)&sA1[sr * KP + sh * 16]     = p0;
            *(short8*)&sA1[sr * KP + sh * 16 + 8] = p1;
            const float4* wq = (const float4*)&w2[(size_t)(o0 + sr) * CCH + k0 + sh * 16];
            float4 d0 = wq[0], d1 = wq[1], d2 = wq[2], d3 = wq[3];
            short8 q0 = {(short)f2bf(d0.x),(short)f2bf(d0.y),(short)f2bf(d0.z),(short)f2bf(d0.w),
                         (short)f2bf(d1.x),(short)f2bf(d1.y),(short)f2bf(d1.z),(short)f2bf(d1.w)};
            short8 q1 = {(short)f2bf(d2.x),(short)f2bf(d2.y),(short)f2bf(d2.z),(short)f2bf(d2.w),
                         (short)f2bf(d3.x),(short)f2bf(d3.y),(short)f2bf(d3.z),(short)f2bf(d3.w)};
            *(short8*)&sA2[sr * KP + sh * 16]     = q0;
            *(short8*)&sA2[sr * KP + sh * 16 + 8] = q1;
        }
        __syncthreads();
        short8 a1[2], a2[2], bf[4];
        #pragma unroll
        for (int io = 0; io < 2; ++io) {
            a1[io] = *(const short8*)&sA1[(wv * 32 + io * 16 + m) * KP + quad * 8];
            a2[io] = *(const short8*)&sA2[(wv * 32 + io * 16 + m) * KP + quad * 8];
        }
        #pragma unroll
        for (int jl = 0; jl < 4; ++jl)
            bf[jl] = *(const short8*)&sB[(jl * 16 + m) * KP + quad * 8];
        #pragma unroll
        for (int io = 0; io < 2; ++io)
            #pragma unroll
            for (int jl = 0; jl < 4; ++jl) {
                acc1[io][jl] = __builtin_amdgcn_mfma_f32_16x16x32_bf16(a1[io], bf[jl], acc1[io][jl], 0, 0, 0);
                acc2[io][jl] = __builtin_amdgcn_mfma_f32_16x16x32_bf16(a2[io], bf[jl], acc2[io][jl], 0, 0, 0);
            }
    }

    #pragma unroll
    for (int io = 0; io < 2; ++io)
        #pragma unroll
        for (int reg = 0; reg < 4; ++reg) {
            const int o = o0 + wv * 32 + io * 16 + quad * 4 + reg;
            const float bb1 = b1[o], bb2 = b2[o];
            const size_t ro = ((size_t)b * CCH + o) * L + l0 + m;
            #pragma unroll
            for (int jl = 0; jl < 4; ++jl) {
                y1[ro + jl * 16] = acc1[io][jl][reg] + bb1;
                y2[ro + jl * 16] = acc2[io][jl][reg] + bb2;
            }
        }
}

// ---------------------------------------------------------------------------
// Single conv1x1 via bf16 MFMA (unchanged from R5)
// ---------------------------------------------------------------------------
__global__ __launch_bounds__(256, 2) void single_gemm_k(
    const float* __restrict__ x,
    const float* __restrict__ w, const float* __restrict__ bb,
    float* __restrict__ y)
{
    __shared__ short sA[128 * KP];
    __shared__ short sB[64 * KP];

    const int tid = threadIdx.x;
    const int l0 = blockIdx.x * 64;
    const int o0 = blockIdx.y * 128;
    const int b  = blockIdx.z;

    const int wv = tid >> 6;
    const int lane = tid & 63;
    const int m = lane & 15;
    const int quad = lane >> 4;

    const float* xb = x + (size_t)b * CCH * L;

    const int sl = tid & 63, soct = tid >> 6;
    const int sr = tid & 127, sh = tid >> 7;

    f32x4 acc[2][4];
    #pragma unroll
    for (int io = 0; io < 2; ++io)
        #pragma unroll
        for (int jl = 0; jl < 4; ++jl)
            acc[io][jl] = (f32x4){0.f,0.f,0.f,0.f};

    for (int s = 0; s < 8; ++s) {
        const int k0 = s * 32;
        __syncthreads();
        {
            const float* xs = xb + (size_t)(k0 + soct * 8) * L + l0 + sl;
            short8 v;
            #pragma unroll
            for (int j = 0; j < 8; ++j) v[j] = (short)f2bf(xs[(size_t)j * L]);
            *(short8*)&sB[sl * KP + soct * 8] = v;
        }
        {
            const float4* wp = (const float4*)&w[(size_t)(o0 + sr) * CCH + k0 + sh * 16];
            float4 c0 = wp[0], c1 = wp[1], c2 = wp[2], c3 = wp[3];
            short8 p0 = {(short)f2bf(c0.x),(short)f2bf(c0.y),(short)f2bf(c0.z),(short)f2bf(c0.w),
                         (short)f2bf(c1.x),(short)f2bf(c1.y),(short)f2bf(c1.z),(short)f2bf(c1.w)};
            short8 p1 = {(short)f2bf(c2.x),(short)f2bf(c2.y),(short)f2bf(c2.z),(short)f2bf(c2.w),
                         (short)f2bf(c3.x),(short)f2bf(c3.y),(short)f2bf(c3.z),(short)f2bf(c3.w)};
            *(short8*)&sA[sr * KP + sh * 16]     = p0;
            *(short8*)&sA[sr * KP + sh * 16 + 8] = p1;
        }
        __syncthreads();
        short8 a[2], bf[4];
        #pragma unroll
        for (int io = 0; io < 2; ++io)
            a[io] = *(const short8*)&sA[(wv * 32 + io * 16 + m) * KP + quad * 8];
        #pragma unroll
        for (int jl = 0; jl < 4; ++jl)
            bf[jl] = *(const short8*)&sB[(jl * 16 + m) * KP + quad * 8];
        #pragma unroll
        for (int io = 0; io < 2; ++io)
            #pragma unroll
            for (int jl = 0; jl < 4; ++jl)
                acc[io][jl] = __builtin_amdgcn_mfma_f32_16x16x32_bf16(a[io], bf[jl], acc[io][jl], 0, 0, 0);
    }

    #pragma unroll
    for (int io = 0; io < 2; ++io)
        #pragma unroll
        for (int reg = 0; reg < 4; ++reg) {
            const int o = o0 + wv * 32 + io * 16 + quad * 4 + reg;
            const float b0 = bb[o];
            const size_t ro = ((size_t)b * CCH + o) * L + l0 + m;
            #pragma unroll
            for (int jl = 0; jl < 4; ++jl)
                y[ro + jl * 16] = acc[io][jl][reg] + b0;
        }
}

// ---------------------------------------------------------------------------
// BatchNorm stats (single tensor)
// ---------------------------------------------------------------------------
__device__ __forceinline__ void bn_stats_body(
    const float* y, const float* gamma, const float* beta,
    float* scale, float* shift, int c, int tid)
{
    float s = 0.f, s2 = 0.f;
    for (int b = 0; b < NB; ++b) {
        const float4* p = (const float4*)(y + ((size_t)b * CCH + c) * L);
        #pragma unroll
        for (int r = 0; r < 4; ++r) {
            float4 v = p[r * 256 + tid];
            s  += v.x + v.y + v.z + v.w;
            s2 += v.x * v.x + v.y * v.y + v.z * v.z + v.w * v.w;
        }
    }
    #pragma unroll
    for (int off = 32; off > 0; off >>= 1) {
        s  += __shfl_down(s, off);
        s2 += __shfl_down(s2, off);
    }
    __shared__ float red[2][4];
    if ((tid & 63) == 0) { red[0][tid >> 6] = s; red[1][tid >> 6] = s2; }
    __syncthreads();
    if (tid == 0) {
        float S  = red[0][0] + red[0][1] + red[0][2] + red[0][3];
        float S2 = red[1][0] + red[1][1] + red[1][2] + red[1][3];
        const float invN = 1.f / (NB * (float)L);
        float mean = S * invN;
        float var  = S2 * invN - mean * mean;
        float rstd = rsqrtf(var + 1e-5f);
        float g = gamma[c];
        scale[c] = g * rstd;
        shift[c] = beta[c] - mean * g * rstd;
    }
}

__global__ __launch_bounds__(256) void bn_stats_k(
    const float* __restrict__ y, const float* __restrict__ gamma,
    const float* __restrict__ beta,
    float* __restrict__ scale, float* __restrict__ shift)
{
    bn_stats_body(y, gamma, beta, scale, shift, blockIdx.x, threadIdx.x);
}

// two tensors in one launch: blockIdx.x in [0,512)
__global__ __launch_bounds__(256) void bn_stats2_k(
    const float* __restrict__ y1, const float* __restrict__ g1, const float* __restrict__ be1,
    float* __restrict__ sc1, float* __restrict__ sh1,
    const float* __restrict__ y2, const float* __restrict__ g2, const float* __restrict__ be2,
    float* __restrict__ sc2, float* __restrict__ sh2)
{
    const int c = blockIdx.x & 255;
    if (blockIdx.x < 256) bn_stats_body(y1, g1, be1, sc1, sh1, c, threadIdx.x);
    else                  bn_stats_body(y2, g2, be2, sc2, sh2, c, threadIdx.x);
}

// ---------------------------------------------------------------------------
// Attention, two-phase, no atomics. K,Q packed bf16 in one dword; per-window
// center (kc,qc) + (-ln denom) persisted by phase 1 in sCI so phase 2 never
// re-decodes the window center. LDS 64 KB -> 2 blocks/CU.
// ---------------------------------------------------------------------------
__global__ __launch_bounds__(512, 4) void attention_k(
    const float* __restrict__ x,
    const float* __restrict__ y1,
    const float* __restrict__ y2,
    const float* __restrict__ s1sc, const float* __restrict__ s1sh,
    const float* __restrict__ s2sc, const float* __restrict__ s2sh,
    float* __restrict__ pre)
{
    __shared__ unsigned sKQ[L];   // 16 KB: bf16 k (lo), q (hi)
    __shared__ float    sXv[L];   // 16 KB
    __shared__ uint2    sCI[L];   // 32 KB: {packed (kc,qc), bits(-ln S)}

    const int bc = blockIdx.x;
    const int tid = threadIdx.x;
    const int ch = bc & 255;
    const size_t off = (size_t)bc * L;

    const float sc1 = s1sc[ch], sh1 = s1sh[ch];
    const float sc2 = s2sc[ch], sh2 = s2sh[ch];

    const float4* k4 = (const float4*)(y1 + off);
    const float4* q4 = (const float4*)(y2 + off);
    const float4* x4 = (const float4*)(x + off);

    #pragma unroll
    for (int r = 0; r < 2; ++r) {
        int i = r * 512 + tid;
        float4 a = k4[i];
        float4 q = q4[i];
        float kk[4] = {a.x, a.y, a.z, a.w};
        float qq[4] = {q.x, q.y, q.z, q.w};
        #pragma unroll
        for (int u = 0; u < 4; ++u) {
            unsigned pk = f2bf(fmaxf(fmaf(kk[u], sc1, sh1), 0.f));
            unsigned pq = f2bf(fmaxf(fmaf(qq[u], sc2, sh2), 0.f));
            sKQ[i * 4 + u] = pk | (pq << 16);
        }
        ((float4*)sXv)[i] = x4[i];
    }
    __syncthreads();

    // ---- Phase 1: per-window center + -ln(denominator) ----------------
    #pragma unroll
    for (int r = 0; r < 8; ++r) {
        const int lp = r * 512 + tid;
        const int base = 9 * lp;
        float kv[9], qv[9];
        unsigned cw = 0;
        #pragma unroll
        for (int j = 0; j < 9; ++j) {
            int f = base + j;
            int t = f >> 12;
            int l = f & 4095;
            int di = (t * 86) >> 8;     // t/3
            int dj = t - di * 3;
            int ii = (l >> 6) + di - 1;
            int jj = (l & 63) + dj - 1;
            bool ok = ((unsigned)ii < 64u) && ((unsigned)jj < 64u);
            int src = ((ii << 6) + jj) & 4095;
            unsigned w = sKQ[src];
            w = ok ? w : 0u;
            if (j == 4) cw = w;
            kv[j] = bflo(w);
            qv[j] = bfhi(w);
        }
        const float kc = kv[4], qc = qv[4];
        float s01 = __expf(kv[0] * qc + kc * qv[0]) + __expf(kv[1] * qc + kc * qv[1]);
        float s23 = __expf(kv[2] * qc + kc * qv[2]) + __expf(kv[3] * qc + kc * qv[3]);
        float s45 = __expf(kv[4] * qc + kc * qv[4]) + __expf(kv[5] * qc + kc * qv[5]);
        float s67 = __expf(kv[6] * qc + kc * qv[6]) + __expf(kv[7] * qc + kc * qv[7]);
        float s = ((s01 + s23) + (s45 + s67)) + __expf(kv[8] * qc + kc * qv[8]);
        uint2 ci;
        ci.x = cw;
        ci.y = __builtin_bit_cast(unsigned, -__logf(s));
        sCI[lp] = ci;
    }
    __syncthreads();

    // ---- Phase 2: per-output accumulate -------------------------------
    #pragma unroll
    for (int r = 0; r < 8; ++r) {
        const int l = r * 512 + tid;
        const int li = l >> 6, lj = l & 63;
        float acc = 0.f;
        #pragma unroll
        for (int t = 0; t < 9; ++t) {
            const int f = (t << 12) + l;
            const unsigned lp = (unsigned)f / 9u;           // magic-mul
            uint2 ci = sCI[lp];
            const float kc = bflo(ci.x), qc = bfhi(ci.x);
            const float cn = __builtin_bit_cast(float, ci.y);
            const int di = t / 3, dj = t % 3;               // constants
            int ii = li + di - 1;
            int jj = lj + dj - 1;
            bool ok = ((unsigned)ii < 64u) && ((unsigned)jj < 64u);
            int src = ((ii << 6) + jj) & 4095;
            unsigned w = sKQ[src];
            float xj = sXv[src];
            w  = ok ? w : 0u;
            xj = ok ? xj : 0.f;
            const float kj = bflo(w), qj = bfhi(w);
            float e = __expf(fmaf(kj, qc, fmaf(kc, qj, cn)));
            acc = fmaf(e, xj, acc);
        }
        pre[off + l] = acc;
    }
}

// ---------------------------------------------------------------------------
// Final BN apply + ReLU
// ---------------------------------------------------------------------------
__global__ __launch_bounds__(256) void bn_apply_k(
    const float* __restrict__ yf,
    const float* __restrict__ scale, const float* __restrict__ shift,
    float* __restrict__ out)
{
    int i = blockIdx.x * 256 + threadIdx.x;     // float4 index
    int o = (i >> 10) & 255;                    // channel
    float sc = scale[o], sh = shift[o];
    float4 v = ((const float4*)yf)[i];
    v.x = fmaxf(fmaf(v.x, sc, sh), 0.f);
    v.y = fmaxf(fmaf(v.y, sc, sh), 0.f);
    v.z = fmaxf(fmaf(v.z, sc, sh), 0.f);
    v.w = fmaxf(fmaf(v.w, sc, sh), 0.f);
    ((float4*)out)[i] = v;
}

// ---------------------------------------------------------------------------
extern "C" void kernel_launch(void* const* d_in, const int* in_sizes, int n_in,
                              void* d_out, int out_size, void* d_ws, size_t ws_size,
                              hipStream_t stream) {
    const float* x   = (const float*)d_in[0];
    const float* w1  = (const float*)d_in[1];
    const float* b1  = (const float*)d_in[2];
    const float* g1  = (const float*)d_in[3];
    const float* be1 = (const float*)d_in[4];
    const float* w2  = (const float*)d_in[5];
    const float* b2  = (const float*)d_in[6];
    const float* g2  = (const float*)d_in[7];
    const float* be2 = (const float*)d_in[8];
    const float* wf  = (const float*)d_in[9];
    const float* bf  = (const float*)d_in[10];
    const float* gf  = (const float*)d_in[11];
    const float* bef = (const float*)d_in[12];
    float* out = (float*)d_out;

    float* ws = (float*)d_ws;
    const size_t NEL = (size_t)NB * CCH * L;   // 4194304
    float* y1 = ws;                 // conv1 out; later reused for yf
    float* y2 = ws + NEL;           // conv2 out; later reused for pre
    float* st = ws + 2 * NEL;       // stats: 6 x 256
    float* s1sc = st,        *s1sh = st + 256;
    float* s2sc = st + 512,  *s2sh = st + 768;
    float* sfsc = st + 1024, *sfsh = st + 1280;

    dim3 gg(64, 2, 4);
    dual_gemm_k<<<gg, 256, 0, stream>>>(x, w1, b1, w2, b2, y1, y2);
    bn_stats2_k<<<512, 256, 0, stream>>>(y1, g1, be1, s1sc, s1sh,
                                         y2, g2, be2, s2sc, s2sh);
    attention_k<<<NB * CCH, 512, 0, stream>>>(x, y1, y2, s1sc, s1sh, s2sc, s2sh, /*pre=*/y2);
    single_gemm_k<<<gg, 256, 0, stream>>>(/*pre=*/y2, wf, bf, /*yf=*/y1);
    bn_stats_k<<<256, 256, 0, stream>>>(y1, gf, bef, sfsc, sfsh);
    bn_apply_k<<<4096, 256, 0, stream>>>(y1, sfsc, sfsh, out);
}